// Round 1
// baseline (130.839 us; speedup 1.0000x reference)
//
#include <hip/hip_runtime.h>
#include <math.h>

// Problem dims (fixed by setup_inputs)
#define B_ 4
#define G_ 8
#define D_ 8
#define H_ 256
#define W_ 320
#define N_ 9
constexpr int HW  = H_ * W_;
constexpr int DHW = D_ * HW;
constexpr float BN_EPS = 1e-5f;

// ---------------- Kernel 1: per-element xnorm + SimilarityNet s ----------------
__global__ __launch_bounds__(256) void k_s_xnorm(
    const float* __restrict__ cost,      // [B,G,D,H,W]
    const float* __restrict__ dsamp,     // [B,D,H,W]
    const float* __restrict__ dmin,      // [B]
    const float* __restrict__ dmax,      // [B]
    const float* __restrict__ w0,        // [16,G]
    const float* __restrict__ g0, const float* __restrict__ b0,
    const float* __restrict__ m0, const float* __restrict__ v0,
    const float* __restrict__ w1,        // [8,16]
    const float* __restrict__ g1, const float* __restrict__ b1,
    const float* __restrict__ m1, const float* __restrict__ v1,
    const float* __restrict__ w2,        // [1,8]
    const float* __restrict__ b2,        // [1]
    float* __restrict__ xn_out,          // [B,D,H,W]
    float* __restrict__ s_out)           // [B,D,H,W]
{
    int idx = blockIdx.x * blockDim.x + threadIdx.x;
    if (idx >= B_ * DHW) return;
    int b   = idx / DHW;
    int d   = (idx / HW) % D_;
    int pix = idx % HW;

    // ---- xnorm ----
    float inv_min = 1.0f / dmin[b];
    float inv_max = 1.0f / dmax[b];
    float xn = (1.0f / dsamp[idx] - inv_max) / (inv_min - inv_max);
    xn_out[idx] = xn;

    // ---- load G cost channels (coalesced per g) ----
    float c[G_];
    const float* cp = cost + ((size_t)b * G_ * D_ + d) * HW + pix;
#pragma unroll
    for (int g = 0; g < G_; ++g) c[g] = cp[(size_t)g * DHW];

    // ---- layer 0: G -> 16, BN fold + relu ----
    float h0[16];
#pragma unroll
    for (int o = 0; o < 16; ++o) {
        float acc = 0.0f;
#pragma unroll
        for (int g = 0; g < G_; ++g) acc = fmaf(c[g], w0[o * G_ + g], acc);
        float inv   = g0[o] / sqrtf(v0[o] + BN_EPS);
        float shift = b0[o] - m0[o] * inv;
        h0[o] = fmaxf(fmaf(acc, inv, shift), 0.0f);
    }

    // ---- layer 1: 16 -> 8, BN fold + relu ----
    float h1[8];
#pragma unroll
    for (int o = 0; o < 8; ++o) {
        float acc = 0.0f;
#pragma unroll
        for (int i = 0; i < 16; ++i) acc = fmaf(h0[i], w1[o * 16 + i], acc);
        float inv   = g1[o] / sqrtf(v1[o] + BN_EPS);
        float shift = b1[o] - m1[o] * inv;
        h1[o] = fmaxf(fmaf(acc, inv, shift), 0.0f);
    }

    // ---- layer 2: 8 -> 1 ----
    float s = b2[0];
#pragma unroll
    for (int i = 0; i < 8; ++i) s = fmaf(h1[i], w2[i], s);
    s_out[idx] = s;
}

// ---------------- Kernel 2: neighbor gather + sigmoid kernel + aggregate ----------------
__global__ __launch_bounds__(256) void k_aggregate(
    const float* __restrict__ grid,      // [B, N*H, W, 2]
    const float* __restrict__ fweight,   // [B, N, H, W]
    const float* __restrict__ xn,        // [B,D,H,W]
    const float* __restrict__ sv,        // [B,D,H,W]
    float* __restrict__ out)             // [B,D,H,W]
{
    int idx = blockIdx.x * blockDim.x + threadIdx.x;   // over B*H*W
    if (idx >= B_ * HW) return;
    int b   = idx / HW;
    int pix = idx % HW;
    int h   = pix / W_;
    int wq  = pix % W_;

    // center xnorm per depth
    float xnc[D_];
#pragma unroll
    for (int d = 0; d < D_; ++d) xnc[d] = xn[(b * D_ + d) * HW + pix];

    float acc[D_];
#pragma unroll
    for (int d = 0; d < D_; ++d) acc[d] = 0.0f;

    const float2* gp = (const float2*)grid;

    for (int n = 0; n < N_; ++n) {
        float2 g = gp[(b * (N_ * H_) + n * H_ + h) * W_ + wq];
        // align_corners=False, border padding
        float gxp = fminf(fmaxf((g.x + 1.0f) * 0.5f * W_ - 0.5f, 0.0f), (float)(W_ - 1));
        float gyp = fminf(fmaxf((g.y + 1.0f) * 0.5f * H_ - 0.5f, 0.0f), (float)(H_ - 1));
        float x0f = floorf(gxp);
        float y0f = floorf(gyp);
        float wx = gxp - x0f;
        float wy = gyp - y0f;
        int x0 = (int)x0f;
        int y0 = (int)y0f;
        int x1 = min(x0 + 1, W_ - 1);
        int y1 = min(y0 + 1, H_ - 1);
        float w00 = (1.0f - wx) * (1.0f - wy);
        float w01 = wx * (1.0f - wy);
        float w10 = (1.0f - wx) * wy;
        float w11 = wx * wy;

        float fw = fweight[((b * N_ + n) * H_ + h) * W_ + wq];

        int o00 = y0 * W_ + x0;
        int o01 = y0 * W_ + x1;
        int o10 = y1 * W_ + x0;
        int o11 = y1 * W_ + x1;

#pragma unroll
        for (int d = 0; d < D_; ++d) {
            int plane = (b * D_ + d) * HW;
            float xs = w00 * xn[plane + o00] + w01 * xn[plane + o01]
                     + w10 * xn[plane + o10] + w11 * xn[plane + o11];
            float ss = w00 * sv[plane + o00] + w01 * sv[plane + o01]
                     + w10 * sv[plane + o10] + w11 * sv[plane + o11];
            float diff = fminf(fabsf(xs - xnc[d]) * 40.0f, 4.0f);   // /0.025, clip 4
            float dw = 1.0f / (1.0f + __expf(2.0f * diff - 4.0f));  // sigmoid((2-diff)*2)
            acc[d] = fmaf(ss * fw, dw, acc[d]);
        }
    }

#pragma unroll
    for (int d = 0; d < D_; ++d) out[(b * D_ + d) * HW + pix] = acc[d];
}

extern "C" void kernel_launch(void* const* d_in, const int* in_sizes, int n_in,
                              void* d_out, int out_size, void* d_ws, size_t ws_size,
                              hipStream_t stream) {
    const float* cost    = (const float*)d_in[0];
    const float* dsamp   = (const float*)d_in[1];
    const float* dmin    = (const float*)d_in[2];
    const float* dmax    = (const float*)d_in[3];
    const float* grid    = (const float*)d_in[4];
    const float* fweight = (const float*)d_in[5];
    const float* w0 = (const float*)d_in[6];
    const float* g0 = (const float*)d_in[7];
    const float* b0 = (const float*)d_in[8];
    const float* m0 = (const float*)d_in[9];
    const float* v0 = (const float*)d_in[10];
    const float* w1 = (const float*)d_in[11];
    const float* g1 = (const float*)d_in[12];
    const float* b1 = (const float*)d_in[13];
    const float* m1 = (const float*)d_in[14];
    const float* v1 = (const float*)d_in[15];
    const float* w2 = (const float*)d_in[16];
    const float* b2 = (const float*)d_in[17];
    float* out = (float*)d_out;

    float* xn = (float*)d_ws;                 // [B,D,H,W]
    float* sv = xn + (size_t)B_ * DHW;        // [B,D,H,W]

    {
        int total = B_ * DHW;
        int block = 256;
        int gridsz = (total + block - 1) / block;
        k_s_xnorm<<<gridsz, block, 0, stream>>>(cost, dsamp, dmin, dmax,
                                                w0, g0, b0, m0, v0,
                                                w1, g1, b1, m1, v1,
                                                w2, b2, xn, sv);
    }
    {
        int total = B_ * HW;
        int block = 256;
        int gridsz = (total + block - 1) / block;
        k_aggregate<<<gridsz, block, 0, stream>>>(grid, fweight, xn, sv, out);
    }
}

// Round 2
// 117.325 us; speedup vs baseline: 1.1152x; 1.1152x over previous
//
#include <hip/hip_runtime.h>
#include <math.h>

// Problem dims (fixed by setup_inputs)
#define B_ 4
#define G_ 8
#define D_ 8
#define H_ 256
#define W_ 320
#define N_ 9
constexpr int HW  = H_ * W_;
constexpr int DHW = D_ * HW;
constexpr float BN_EPS = 1e-5f;

// d_ws float layout:
//   [0..127]    fw0[16][8]   (BN-folded layer0 weights)
//   [128..143]  fb0[16]      (BN-folded layer0 bias)
//   [144..271]  fw1[8][16]
//   [272..279]  fb1[8]
//   [280..287]  fw2[8]
//   [288]       fb2
//   [292..295]  sc[B]        (xnorm scale per batch)
//   [296..299]  ofs[B]       (xnorm offset per batch)
//   [320...]    pair buffer: [B][HW][D] float2 {xn, s}  (21.0 MB)
#define WS_PAIR_OFF 320

// ---------------- Kernel 0: fold BN into weights, precompute xnorm affine ----------------
__global__ void k_setup(
    const float* __restrict__ dmin, const float* __restrict__ dmax,
    const float* __restrict__ w0, const float* __restrict__ g0, const float* __restrict__ b0,
    const float* __restrict__ m0, const float* __restrict__ v0,
    const float* __restrict__ w1, const float* __restrict__ g1, const float* __restrict__ b1,
    const float* __restrict__ m1, const float* __restrict__ v1,
    const float* __restrict__ w2, const float* __restrict__ b2,
    float* __restrict__ ws)
{
    int t = threadIdx.x;
    if (t < 16) {
        float inv   = g0[t] * rsqrtf(v0[t] + BN_EPS);
        float shift = b0[t] - m0[t] * inv;
        for (int g = 0; g < G_; ++g) ws[t * G_ + g] = w0[t * G_ + g] * inv;
        ws[128 + t] = shift;
    }
    if (t < 8) {
        float inv   = g1[t] * rsqrtf(v1[t] + BN_EPS);
        float shift = b1[t] - m1[t] * inv;
        for (int i = 0; i < 16; ++i) ws[144 + t * 16 + i] = w1[t * 16 + i] * inv;
        ws[272 + t] = shift;
        ws[280 + t] = w2[t];
    }
    if (t == 0) ws[288] = b2[0];
    if (t < B_) {
        float imin = 1.0f / dmin[t];
        float imax = 1.0f / dmax[t];
        float sc   = 1.0f / (imin - imax);
        ws[292 + t] = sc;
        ws[296 + t] = -imax * sc;
    }
}

// ---------------- Kernel 1: per-pixel xnorm + SimilarityNet s (all 8 depths) ----------------
__global__ __launch_bounds__(256) void k_s_xnorm(
    const float* __restrict__ cost,      // [B,G,D,H,W]
    const float* __restrict__ dsamp,     // [B,D,H,W]
    const float* __restrict__ ws,
    float2* __restrict__ pair)           // [B*HW*D] {xn, s}
{
    int idx = blockIdx.x * blockDim.x + threadIdx.x;   // over B*H*W
    if (idx >= B_ * HW) return;
    int b   = idx / HW;
    int pix = idx % HW;

    float sc  = ws[292 + b];
    float ofs = ws[296 + b];

    const float* cbase = cost  + (size_t)b * G_ * DHW + pix;
    const float* dbase = dsamp + (size_t)b * DHW + pix;

    float2 outp[D_];
#pragma unroll
    for (int d = 0; d < D_; ++d) {
        float c[G_];
#pragma unroll
        for (int g = 0; g < G_; ++g) c[g] = cbase[(size_t)(g * D_ + d) * HW];

        float h0[16];
#pragma unroll
        for (int o = 0; o < 16; ++o) {
            float acc = ws[128 + o];
#pragma unroll
            for (int g = 0; g < G_; ++g) acc = fmaf(c[g], ws[o * G_ + g], acc);
            h0[o] = fmaxf(acc, 0.0f);
        }
        float h1[8];
#pragma unroll
        for (int o = 0; o < 8; ++o) {
            float acc = ws[272 + o];
#pragma unroll
            for (int i = 0; i < 16; ++i) acc = fmaf(h0[i], ws[144 + o * 16 + i], acc);
            h1[o] = fmaxf(acc, 0.0f);
        }
        float s = ws[288];
#pragma unroll
        for (int i = 0; i < 8; ++i) s = fmaf(h1[i], ws[280 + i], s);

        float xn = fmaf(__builtin_amdgcn_rcpf(dbase[(size_t)d * HW]), sc, ofs);
        outp[d].x = xn;
        outp[d].y = s;
    }

    float4* pp = (float4*)(pair + (size_t)idx * D_);
    const float4* op = (const float4*)outp;
#pragma unroll
    for (int j = 0; j < 4; ++j) pp[j] = op[j];
}

// ---------------- Kernel 2: neighbor gather + sigmoid kernel + aggregate ----------------
__global__ __launch_bounds__(256) void k_aggregate(
    const float* __restrict__ grid,      // [B, N*H, W, 2]
    const float* __restrict__ fweight,   // [B, N, H, W]
    const float4* __restrict__ pair4,    // [B*HW*4] each float4 = 2 depths of {xn,s}
    float* __restrict__ out)             // [B,D,H,W]
{
    int idx = blockIdx.x * blockDim.x + threadIdx.x;   // over B*H*W
    if (idx >= B_ * HW) return;
    int b   = idx / HW;
    int pix = idx % HW;
    int h   = pix / W_;
    int wq  = pix % W_;

    // center xnorm per depth (from interleaved pairs)
    float xnc[D_];
    {
        const float4* cp = pair4 + (size_t)idx * 4;
#pragma unroll
        for (int j = 0; j < 4; ++j) {
            float4 v = cp[j];
            xnc[2 * j]     = v.x;
            xnc[2 * j + 1] = v.z;
        }
    }

    float acc[D_];
#pragma unroll
    for (int d = 0; d < D_; ++d) acc[d] = 0.0f;

    const float2* gp = (const float2*)grid;
    const int bbase = b * HW;

    for (int n = 0; n < N_; ++n) {
        float2 g = gp[(b * (N_ * H_) + n * H_ + h) * W_ + wq];
        // align_corners=False, border padding
        float gxp = fminf(fmaxf((g.x + 1.0f) * 0.5f * W_ - 0.5f, 0.0f), (float)(W_ - 1));
        float gyp = fminf(fmaxf((g.y + 1.0f) * 0.5f * H_ - 0.5f, 0.0f), (float)(H_ - 1));
        float x0f = floorf(gxp);
        float y0f = floorf(gyp);
        float wx = gxp - x0f;
        float wy = gyp - y0f;
        int x0 = (int)x0f;
        int y0 = (int)y0f;
        int x1 = min(x0 + 1, W_ - 1);
        int y1 = min(y0 + 1, H_ - 1);
        float w00 = (1.0f - wx) * (1.0f - wy);
        float w01 = wx * (1.0f - wy);
        float w10 = (1.0f - wx) * wy;
        float w11 = wx * wy;

        float fw = fweight[((b * N_ + n) * H_ + h) * W_ + wq];

        const float4* t00 = pair4 + (size_t)(bbase + y0 * W_ + x0) * 4;
        const float4* t01 = pair4 + (size_t)(bbase + y0 * W_ + x1) * 4;
        const float4* t10 = pair4 + (size_t)(bbase + y1 * W_ + x0) * 4;
        const float4* t11 = pair4 + (size_t)(bbase + y1 * W_ + x1) * 4;

#pragma unroll
        for (int j = 0; j < 4; ++j) {
            float4 a = t00[j];
            float4 p = t01[j];
            float4 q = t10[j];
            float4 r = t11[j];
            // depth 2j: components .x (xn), .y (s); depth 2j+1: .z, .w
            float xs0 = w00 * a.x + w01 * p.x + w10 * q.x + w11 * r.x;
            float ss0 = w00 * a.y + w01 * p.y + w10 * q.y + w11 * r.y;
            float xs1 = w00 * a.z + w01 * p.z + w10 * q.z + w11 * r.z;
            float ss1 = w00 * a.w + w01 * p.w + w10 * q.w + w11 * r.w;

            float df0 = fminf(fabsf(xs0 - xnc[2 * j]) * 40.0f, 4.0f);
            float df1 = fminf(fabsf(xs1 - xnc[2 * j + 1]) * 40.0f, 4.0f);
            float dw0 = __builtin_amdgcn_rcpf(1.0f + __expf(2.0f * df0 - 4.0f));
            float dw1 = __builtin_amdgcn_rcpf(1.0f + __expf(2.0f * df1 - 4.0f));
            acc[2 * j]     = fmaf(ss0 * fw, dw0, acc[2 * j]);
            acc[2 * j + 1] = fmaf(ss1 * fw, dw1, acc[2 * j + 1]);
        }
    }

#pragma unroll
    for (int d = 0; d < D_; ++d) out[(b * D_ + d) * HW + pix] = acc[d];
}

extern "C" void kernel_launch(void* const* d_in, const int* in_sizes, int n_in,
                              void* d_out, int out_size, void* d_ws, size_t ws_size,
                              hipStream_t stream) {
    const float* cost    = (const float*)d_in[0];
    const float* dsamp   = (const float*)d_in[1];
    const float* dmin    = (const float*)d_in[2];
    const float* dmax    = (const float*)d_in[3];
    const float* grid    = (const float*)d_in[4];
    const float* fweight = (const float*)d_in[5];
    const float* w0 = (const float*)d_in[6];
    const float* g0 = (const float*)d_in[7];
    const float* b0 = (const float*)d_in[8];
    const float* m0 = (const float*)d_in[9];
    const float* v0 = (const float*)d_in[10];
    const float* w1 = (const float*)d_in[11];
    const float* g1 = (const float*)d_in[12];
    const float* b1 = (const float*)d_in[13];
    const float* m1 = (const float*)d_in[14];
    const float* v1 = (const float*)d_in[15];
    const float* w2 = (const float*)d_in[16];
    const float* b2 = (const float*)d_in[17];
    float* out = (float*)d_out;

    float*  ws   = (float*)d_ws;
    float2* pair = (float2*)(ws + WS_PAIR_OFF);

    k_setup<<<1, 64, 0, stream>>>(dmin, dmax,
                                  w0, g0, b0, m0, v0,
                                  w1, g1, b1, m1, v1,
                                  w2, b2, ws);

    {
        int total = B_ * HW;
        int block = 256;
        int gridsz = (total + block - 1) / block;
        k_s_xnorm<<<gridsz, block, 0, stream>>>(cost, dsamp, ws, pair);
    }
    {
        int total = B_ * HW;
        int block = 256;
        int gridsz = (total + block - 1) / block;
        k_aggregate<<<gridsz, block, 0, stream>>>(grid, fweight, (const float4*)pair, out);
    }
}

// Round 3
// 116.554 us; speedup vs baseline: 1.1226x; 1.0066x over previous
//
#include <hip/hip_runtime.h>
#include <math.h>

// Problem dims (fixed by setup_inputs)
#define B_ 4
#define G_ 8
#define D_ 8
#define H_ 256
#define W_ 320
#define N_ 9
constexpr int HW  = H_ * W_;
constexpr int DHW = D_ * HW;
constexpr float BN_EPS = 1e-5f;

// d_ws float layout:
//   [0..127]    fw0[16][8]   (BN-folded layer0 weights)
//   [128..143]  fb0[16]      (BN-folded layer0 bias)
//   [144..271]  fw1[8][16]
//   [272..279]  fb1[8]
//   [280..287]  fw2[8]
//   [288]       fb2
//   [292..295]  sc[B]        (xnorm scale per batch)
//   [296..299]  ofs[B]       (xnorm offset per batch)
//   [320...]    pair buffer: [B][HW][D] float2 {xn, s}  (21.0 MB)
#define WS_PAIR_OFF 320

// XCD band swizzle: hardware dispatches blockIdx round-robin to 8 XCDs
// (xcd = bid % 8). Remap so each XCD owns a contiguous pixel band ->
// its 2.6 MB pair slice (+halo) stays resident in its 4 MiB L2 across
// all 9 neighbor passes. nblocks must be divisible by 8 (1280 = 8*160).
__device__ __forceinline__ int swz_band(int bid, int per_xcd) {
    return (bid & 7) * per_xcd + (bid >> 3);
}

// ---------------- Kernel 0: fold BN into weights, precompute xnorm affine ----------------
__global__ void k_setup(
    const float* __restrict__ dmin, const float* __restrict__ dmax,
    const float* __restrict__ w0, const float* __restrict__ g0, const float* __restrict__ b0,
    const float* __restrict__ m0, const float* __restrict__ v0,
    const float* __restrict__ w1, const float* __restrict__ g1, const float* __restrict__ b1,
    const float* __restrict__ m1, const float* __restrict__ v1,
    const float* __restrict__ w2, const float* __restrict__ b2,
    float* __restrict__ ws)
{
    int t = threadIdx.x;
    if (t < 16) {
        float inv   = g0[t] * rsqrtf(v0[t] + BN_EPS);
        float shift = b0[t] - m0[t] * inv;
        for (int g = 0; g < G_; ++g) ws[t * G_ + g] = w0[t * G_ + g] * inv;
        ws[128 + t] = shift;
    }
    if (t < 8) {
        float inv   = g1[t] * rsqrtf(v1[t] + BN_EPS);
        float shift = b1[t] - m1[t] * inv;
        for (int i = 0; i < 16; ++i) ws[144 + t * 16 + i] = w1[t * 16 + i] * inv;
        ws[272 + t] = shift;
        ws[280 + t] = w2[t];
    }
    if (t == 0) ws[288] = b2[0];
    if (t < B_) {
        float imin = 1.0f / dmin[t];
        float imax = 1.0f / dmax[t];
        float sc   = 1.0f / (imin - imax);
        ws[292 + t] = sc;
        ws[296 + t] = -imax * sc;
    }
}

// ---------------- MLP for one pixel-depth: G costs -> s ----------------
__device__ __forceinline__ float mlp_eval(const float c[G_], const float* __restrict__ ws) {
    float h0[16];
#pragma unroll
    for (int o = 0; o < 16; ++o) {
        float acc = ws[128 + o];
#pragma unroll
        for (int g = 0; g < G_; ++g) acc = fmaf(c[g], ws[o * G_ + g], acc);
        h0[o] = fmaxf(acc, 0.0f);
    }
    float h1[8];
#pragma unroll
    for (int o = 0; o < 8; ++o) {
        float acc = ws[272 + o];
#pragma unroll
        for (int i = 0; i < 16; ++i) acc = fmaf(h0[i], ws[144 + o * 16 + i], acc);
        h1[o] = fmaxf(acc, 0.0f);
    }
    float s = ws[288];
#pragma unroll
    for (int i = 0; i < 8; ++i) s = fmaf(h1[i], ws[280 + i], s);
    return s;
}

// ---------------- Kernel 1: per-pixel xnorm + SimilarityNet s (2 px/thread) ----------------
__global__ __launch_bounds__(128) void k_s_xnorm(
    const float* __restrict__ cost,      // [B,G,D,H,W]
    const float* __restrict__ dsamp,     // [B,D,H,W]
    const float* __restrict__ ws,
    float2* __restrict__ pair)           // [B*HW*D] {xn, s}
{
    int bid  = swz_band(blockIdx.x, 160);          // 1280 blocks, 256 px each
    int pix0 = bid * 256 + threadIdx.x * 2;        // global pixel (b*HW + pix), even
    int b    = pix0 / HW;
    int pix  = pix0 % HW;

    float sc  = ws[292 + b];
    float ofs = ws[296 + b];

    const float* cb = cost  + (size_t)b * G_ * DHW + pix;
    const float* db = dsamp + (size_t)b * DHW + pix;

    float2 o0[D_], o1[D_];                         // {xn, s} per depth, 2 pixels
#pragma unroll
    for (int d = 0; d < D_; ++d) {
        float2 c2[G_];
#pragma unroll
        for (int g = 0; g < G_; ++g)
            c2[g] = *(const float2*)(cb + (size_t)(g * D_ + d) * HW);

        float ca[G_], cbx[G_];
#pragma unroll
        for (int g = 0; g < G_; ++g) { ca[g] = c2[g].x; cbx[g] = c2[g].y; }

        float s0 = mlp_eval(ca,  ws);
        float s1 = mlp_eval(cbx, ws);

        float2 ds = *(const float2*)(db + (size_t)d * HW);
        o0[d].x = fmaf(__builtin_amdgcn_rcpf(ds.x), sc, ofs);
        o0[d].y = s0;
        o1[d].x = fmaf(__builtin_amdgcn_rcpf(ds.y), sc, ofs);
        o1[d].y = s1;
    }

    // two pixels are contiguous in the pair buffer: 8 consecutive float4 stores
    float4* pp = (float4*)(pair + (size_t)pix0 * D_);
    const float4* s0p = (const float4*)o0;
    const float4* s1p = (const float4*)o1;
#pragma unroll
    for (int j = 0; j < 4; ++j) pp[j] = s0p[j];
#pragma unroll
    for (int j = 0; j < 4; ++j) pp[4 + j] = s1p[j];
}

// ---------------- Kernel 2: neighbor gather + sigmoid kernel + aggregate ----------------
__global__ __launch_bounds__(256) void k_aggregate(
    const float* __restrict__ grid,      // [B, N*H, W, 2]
    const float* __restrict__ fweight,   // [B, N, H, W]
    const float4* __restrict__ pair4,    // [B*HW*4] each float4 = 2 depths of {xn,s}
    float* __restrict__ out)             // [B,D,H,W]
{
    int bid = swz_band(blockIdx.x, 160);           // 1280 blocks, 256 px each
    int idx = bid * 256 + threadIdx.x;             // over B*H*W
    int b   = idx / HW;
    int pix = idx % HW;
    int h   = pix / W_;
    int wq  = pix % W_;

    // center xnorm per depth (from interleaved pairs)
    float xnc[D_];
    {
        const float4* cp = pair4 + (size_t)idx * 4;
#pragma unroll
        for (int j = 0; j < 4; ++j) {
            float4 v = cp[j];
            xnc[2 * j]     = v.x;
            xnc[2 * j + 1] = v.z;
        }
    }

    float acc[D_];
#pragma unroll
    for (int d = 0; d < D_; ++d) acc[d] = 0.0f;

    const float2* gp = (const float2*)grid;
    const int bbase = b * HW;

    for (int n = 0; n < N_; ++n) {
        float2 g = gp[(b * (N_ * H_) + n * H_ + h) * W_ + wq];
        // align_corners=False, border padding
        float gxp = fminf(fmaxf((g.x + 1.0f) * 0.5f * W_ - 0.5f, 0.0f), (float)(W_ - 1));
        float gyp = fminf(fmaxf((g.y + 1.0f) * 0.5f * H_ - 0.5f, 0.0f), (float)(H_ - 1));
        float x0f = floorf(gxp);
        float y0f = floorf(gyp);
        float wx = gxp - x0f;
        float wy = gyp - y0f;
        int x0 = (int)x0f;
        int y0 = (int)y0f;
        int x1 = min(x0 + 1, W_ - 1);
        int y1 = min(y0 + 1, H_ - 1);
        float w00 = (1.0f - wx) * (1.0f - wy);
        float w01 = wx * (1.0f - wy);
        float w10 = (1.0f - wx) * wy;
        float w11 = wx * wy;

        float fw = fweight[((b * N_ + n) * H_ + h) * W_ + wq];

        const float4* t00 = pair4 + (size_t)(bbase + y0 * W_ + x0) * 4;
        const float4* t01 = pair4 + (size_t)(bbase + y0 * W_ + x1) * 4;
        const float4* t10 = pair4 + (size_t)(bbase + y1 * W_ + x0) * 4;
        const float4* t11 = pair4 + (size_t)(bbase + y1 * W_ + x1) * 4;

#pragma unroll
        for (int j = 0; j < 4; ++j) {
            float4 a = t00[j];
            float4 p = t01[j];
            float4 q = t10[j];
            float4 r = t11[j];
            // depth 2j: components .x (xn), .y (s); depth 2j+1: .z, .w
            float xs0 = w00 * a.x + w01 * p.x + w10 * q.x + w11 * r.x;
            float ss0 = w00 * a.y + w01 * p.y + w10 * q.y + w11 * r.y;
            float xs1 = w00 * a.z + w01 * p.z + w10 * q.z + w11 * r.z;
            float ss1 = w00 * a.w + w01 * p.w + w10 * q.w + w11 * r.w;

            float df0 = fminf(fabsf(xs0 - xnc[2 * j]) * 40.0f, 4.0f);
            float df1 = fminf(fabsf(xs1 - xnc[2 * j + 1]) * 40.0f, 4.0f);
            float dw0 = __builtin_amdgcn_rcpf(1.0f + __expf(2.0f * df0 - 4.0f));
            float dw1 = __builtin_amdgcn_rcpf(1.0f + __expf(2.0f * df1 - 4.0f));
            acc[2 * j]     = fmaf(ss0 * fw, dw0, acc[2 * j]);
            acc[2 * j + 1] = fmaf(ss1 * fw, dw1, acc[2 * j + 1]);
        }
    }

#pragma unroll
    for (int d = 0; d < D_; ++d) out[(b * D_ + d) * HW + pix] = acc[d];
}

extern "C" void kernel_launch(void* const* d_in, const int* in_sizes, int n_in,
                              void* d_out, int out_size, void* d_ws, size_t ws_size,
                              hipStream_t stream) {
    const float* cost    = (const float*)d_in[0];
    const float* dsamp   = (const float*)d_in[1];
    const float* dmin    = (const float*)d_in[2];
    const float* dmax    = (const float*)d_in[3];
    const float* grid    = (const float*)d_in[4];
    const float* fweight = (const float*)d_in[5];
    const float* w0 = (const float*)d_in[6];
    const float* g0 = (const float*)d_in[7];
    const float* b0 = (const float*)d_in[8];
    const float* m0 = (const float*)d_in[9];
    const float* v0 = (const float*)d_in[10];
    const float* w1 = (const float*)d_in[11];
    const float* g1 = (const float*)d_in[12];
    const float* b1 = (const float*)d_in[13];
    const float* m1 = (const float*)d_in[14];
    const float* v1 = (const float*)d_in[15];
    const float* w2 = (const float*)d_in[16];
    const float* b2 = (const float*)d_in[17];
    float* out = (float*)d_out;

    float*  ws   = (float*)d_ws;
    float2* pair = (float2*)(ws + WS_PAIR_OFF);

    k_setup<<<1, 64, 0, stream>>>(dmin, dmax,
                                  w0, g0, b0, m0, v0,
                                  w1, g1, b1, m1, v1,
                                  w2, b2, ws);

    // 1280 blocks each: both kernels use the same band mapping so the XCD
    // that writes a pair band is the XCD that gathers from it.
    k_s_xnorm<<<1280, 128, 0, stream>>>(cost, dsamp, ws, pair);
    k_aggregate<<<1280, 256, 0, stream>>>(grid, fweight, (const float4*)pair, out);
}

// Round 4
// 91.069 us; speedup vs baseline: 1.4367x; 1.2798x over previous
//
#include <hip/hip_runtime.h>
#include <math.h>

// Problem dims (fixed by setup_inputs)
#define B_ 4
#define G_ 8
#define D_ 8
#define H_ 256
#define W_ 320
#define N_ 9
constexpr int HW  = H_ * W_;
constexpr int DHW = D_ * HW;
constexpr int BHW = B_ * HW;
constexpr float BN_EPS = 1e-5f;

// d_ws float layout:
//   [0..127]    fw0[16][8]   (BN-folded layer0 weights)
//   [128..143]  fb0[16]      (BN-folded layer0 bias)
//   [144..271]  fw1[8][16]
//   [272..279]  fb1[8]
//   [280..287]  fw2[8]
//   [288]       fb2
//   [292..295]  sc[B]        (xnorm scale per batch)
//   [296..299]  ofs[B]       (xnorm offset per batch)
//   [320...]    pair planes: float4 plane[4][B*HW], plane j holds
//               {xn(2j), s(2j), xn(2j+1), s(2j+1)} for each pixel (21.0 MB)
#define WS_PAIR_OFF 320

// XCD band swizzle: hardware dispatches blockIdx round-robin to 8 XCDs
// (xcd = bid % 8). Remap so each XCD owns a contiguous pixel band ->
// its 2.6 MB pair slice (+halo) stays resident in its 4 MiB L2 across
// all 9 neighbor passes. nblocks divisible by 8 (1280 = 8*160).
__device__ __forceinline__ int swz_band(int bid, int per_xcd) {
    return (bid & 7) * per_xcd + (bid >> 3);
}

// ---------------- Kernel 0: fold BN into weights, precompute xnorm affine ----------------
__global__ void k_setup(
    const float* __restrict__ dmin, const float* __restrict__ dmax,
    const float* __restrict__ w0, const float* __restrict__ g0, const float* __restrict__ b0,
    const float* __restrict__ m0, const float* __restrict__ v0,
    const float* __restrict__ w1, const float* __restrict__ g1, const float* __restrict__ b1,
    const float* __restrict__ m1, const float* __restrict__ v1,
    const float* __restrict__ w2, const float* __restrict__ b2,
    float* __restrict__ ws)
{
    int t = threadIdx.x;
    if (t < 16) {
        float inv   = g0[t] * rsqrtf(v0[t] + BN_EPS);
        float shift = b0[t] - m0[t] * inv;
        for (int g = 0; g < G_; ++g) ws[t * G_ + g] = w0[t * G_ + g] * inv;
        ws[128 + t] = shift;
    }
    if (t < 8) {
        float inv   = g1[t] * rsqrtf(v1[t] + BN_EPS);
        float shift = b1[t] - m1[t] * inv;
        for (int i = 0; i < 16; ++i) ws[144 + t * 16 + i] = w1[t * 16 + i] * inv;
        ws[272 + t] = shift;
        ws[280 + t] = w2[t];
    }
    if (t == 0) ws[288] = b2[0];
    if (t < B_) {
        float imin = 1.0f / dmin[t];
        float imax = 1.0f / dmax[t];
        float sc   = 1.0f / (imin - imax);
        ws[292 + t] = sc;
        ws[296 + t] = -imax * sc;
    }
}

// ---------------- MLP for one pixel-depth: G costs -> s ----------------
__device__ __forceinline__ float mlp_eval(const float c[G_], const float* __restrict__ ws) {
    float h0[16];
#pragma unroll
    for (int o = 0; o < 16; ++o) {
        float acc = ws[128 + o];
#pragma unroll
        for (int g = 0; g < G_; ++g) acc = fmaf(c[g], ws[o * G_ + g], acc);
        h0[o] = fmaxf(acc, 0.0f);
    }
    float h1[8];
#pragma unroll
    for (int o = 0; o < 8; ++o) {
        float acc = ws[272 + o];
#pragma unroll
        for (int i = 0; i < 16; ++i) acc = fmaf(h0[i], ws[144 + o * 16 + i], acc);
        h1[o] = fmaxf(acc, 0.0f);
    }
    float s = ws[288];
#pragma unroll
    for (int i = 0; i < 8; ++i) s = fmaf(h1[i], ws[280 + i], s);
    return s;
}

// ---------------- Kernel 1: per-pixel xnorm + SimilarityNet s (1 px/thread) ----------------
__global__ __launch_bounds__(256) void k_s_xnorm(
    const float* __restrict__ cost,      // [B,G,D,H,W]
    const float* __restrict__ dsamp,     // [B,D,H,W]
    const float* __restrict__ ws,
    float4* __restrict__ plane)          // [4][B*HW]
{
    int idx = swz_band(blockIdx.x, 160) * 256 + threadIdx.x;  // b*HW + pix
    int b   = idx / HW;
    int pix = idx % HW;

    float sc  = ws[292 + b];
    float ofs = ws[296 + b];

    const float* cb = cost  + (size_t)b * G_ * DHW + pix;
    const float* db = dsamp + (size_t)b * DHW + pix;

    float4 res[4];
#pragma unroll
    for (int d = 0; d < D_; ++d) {
        float c[G_];
#pragma unroll
        for (int g = 0; g < G_; ++g) c[g] = cb[(size_t)(g * D_ + d) * HW];

        float s  = mlp_eval(c, ws);
        float xn = fmaf(__builtin_amdgcn_rcpf(db[(size_t)d * HW]), sc, ofs);

        if ((d & 1) == 0) { res[d >> 1].x = xn; res[d >> 1].y = s; }
        else              { res[d >> 1].z = xn; res[d >> 1].w = s; }
    }

#pragma unroll
    for (int j = 0; j < 4; ++j) plane[(size_t)j * BHW + idx] = res[j];
}

// ---------------- Kernel 2: neighbor gather + sigmoid kernel + aggregate ----------------
__global__ __launch_bounds__(256) void k_aggregate(
    const float* __restrict__ grid,      // [B, N*H, W, 2]
    const float* __restrict__ fweight,   // [B, N, H, W]
    const float4* __restrict__ plane,    // [4][B*HW]
    float* __restrict__ out)             // [B,D,H,W]
{
    int idx = swz_band(blockIdx.x, 160) * 256 + threadIdx.x;  // b*HW + pix
    int b   = idx / HW;
    int pix = idx % HW;
    int h   = pix / W_;
    int wq  = pix % W_;

    // center xnorm per depth (one coalesced float4 per plane)
    float xnc[D_];
#pragma unroll
    for (int j = 0; j < 4; ++j) {
        float4 v = plane[(size_t)j * BHW + idx];
        xnc[2 * j]     = v.x;
        xnc[2 * j + 1] = v.z;
    }

    float acc[D_];
#pragma unroll
    for (int d = 0; d < D_; ++d) acc[d] = 0.0f;

    const float2* gp = (const float2*)grid;
    const int bbase = b * HW;

    for (int n = 0; n < N_; ++n) {
        float2 g = gp[(b * (N_ * H_) + n * H_ + h) * W_ + wq];
        // align_corners=False, border padding
        float gxp = fminf(fmaxf((g.x + 1.0f) * 0.5f * W_ - 0.5f, 0.0f), (float)(W_ - 1));
        float gyp = fminf(fmaxf((g.y + 1.0f) * 0.5f * H_ - 0.5f, 0.0f), (float)(H_ - 1));
        float x0f = floorf(gxp);
        float y0f = floorf(gyp);
        float wx = gxp - x0f;
        float wy = gyp - y0f;
        int x0 = (int)x0f;
        int y0 = (int)y0f;
        int x1 = min(x0 + 1, W_ - 1);
        int y1 = min(y0 + 1, H_ - 1);
        float w00 = (1.0f - wx) * (1.0f - wy);
        float w01 = wx * (1.0f - wy);
        float w10 = (1.0f - wx) * wy;
        float w11 = wx * wy;

        float fw = fweight[((b * N_ + n) * H_ + h) * W_ + wq];

        int o00 = bbase + y0 * W_ + x0;
        int o01 = bbase + y0 * W_ + x1;
        int o10 = bbase + y1 * W_ + x0;
        int o11 = bbase + y1 * W_ + x1;

#pragma unroll
        for (int j = 0; j < 4; ++j) {
            const float4* pj = plane + (size_t)j * BHW;
            float4 a = pj[o00];
            float4 p = pj[o01];
            float4 q = pj[o10];
            float4 r = pj[o11];
            // depth 2j: components .x (xn), .y (s); depth 2j+1: .z, .w
            float xs0 = w00 * a.x + w01 * p.x + w10 * q.x + w11 * r.x;
            float ss0 = w00 * a.y + w01 * p.y + w10 * q.y + w11 * r.y;
            float xs1 = w00 * a.z + w01 * p.z + w10 * q.z + w11 * r.z;
            float ss1 = w00 * a.w + w01 * p.w + w10 * q.w + w11 * r.w;

            float df0 = fminf(fabsf(xs0 - xnc[2 * j]) * 40.0f, 4.0f);
            float df1 = fminf(fabsf(xs1 - xnc[2 * j + 1]) * 40.0f, 4.0f);
            float dw0 = __builtin_amdgcn_rcpf(1.0f + __expf(2.0f * df0 - 4.0f));
            float dw1 = __builtin_amdgcn_rcpf(1.0f + __expf(2.0f * df1 - 4.0f));
            acc[2 * j]     = fmaf(ss0 * fw, dw0, acc[2 * j]);
            acc[2 * j + 1] = fmaf(ss1 * fw, dw1, acc[2 * j + 1]);
        }
    }

#pragma unroll
    for (int d = 0; d < D_; ++d) out[(b * D_ + d) * HW + pix] = acc[d];
}

extern "C" void kernel_launch(void* const* d_in, const int* in_sizes, int n_in,
                              void* d_out, int out_size, void* d_ws, size_t ws_size,
                              hipStream_t stream) {
    const float* cost    = (const float*)d_in[0];
    const float* dsamp   = (const float*)d_in[1];
    const float* dmin    = (const float*)d_in[2];
    const float* dmax    = (const float*)d_in[3];
    const float* grid    = (const float*)d_in[4];
    const float* fweight = (const float*)d_in[5];
    const float* w0 = (const float*)d_in[6];
    const float* g0 = (const float*)d_in[7];
    const float* b0 = (const float*)d_in[8];
    const float* m0 = (const float*)d_in[9];
    const float* v0 = (const float*)d_in[10];
    const float* w1 = (const float*)d_in[11];
    const float* g1 = (const float*)d_in[12];
    const float* b1 = (const float*)d_in[13];
    const float* m1 = (const float*)d_in[14];
    const float* v1 = (const float*)d_in[15];
    const float* w2 = (const float*)d_in[16];
    const float* b2 = (const float*)d_in[17];
    float* out = (float*)d_out;

    float*  ws    = (float*)d_ws;
    float4* plane = (float4*)(ws + WS_PAIR_OFF);

    k_setup<<<1, 64, 0, stream>>>(dmin, dmax,
                                  w0, g0, b0, m0, v0,
                                  w1, g1, b1, m1, v1,
                                  w2, b2, ws);

    // 1280 blocks each, identical band mapping: the XCD that writes a pair
    // band is the XCD that gathers from it.
    k_s_xnorm<<<1280, 256, 0, stream>>>(cost, dsamp, ws, plane);
    k_aggregate<<<1280, 256, 0, stream>>>(grid, fweight, plane, out);
}

// Round 5
// 70.287 us; speedup vs baseline: 1.8615x; 1.2957x over previous
//
#include <hip/hip_runtime.h>
#include <math.h>

// Problem dims (fixed by setup_inputs)
#define B_ 4
#define G_ 8
#define D_ 8
#define H_ 256
#define W_ 320
#define N_ 9
constexpr int HW  = H_ * W_;
constexpr int DHW = D_ * HW;
constexpr int BHW = B_ * HW;
constexpr float BN_EPS = 1e-5f;

// d_ws float layout:
//   [0..127]    fw0[16][8]   (BN-folded layer0 weights)
//   [128..143]  fb0[16]      (BN-folded layer0 bias)
//   [144..271]  fw1[8][16]
//   [272..279]  fb1[8]
//   [280..287]  fw2[8]
//   [288]       fb2
//   [292..295]  sc[B]        (xnorm scale per batch)
//   [296..299]  ofs[B]       (xnorm offset per batch)
//   [320...]    pair planes: float4 plane[4][B*HW], plane j holds
//               {xn(2j), s(2j), xn(2j+1), s(2j+1)} for each pixel (21.0 MB)
#define WS_PAIR_OFF 320

// XCD band swizzle: hardware dispatches blockIdx round-robin to 8 XCDs
// (xcd = bid % 8). Remap so each XCD owns a contiguous pixel band ->
// its 2.6 MB pair slice (+halo) stays resident in its 4 MiB L2 across
// all 9 neighbor passes. nblocks must be divisible by 8.
__device__ __forceinline__ int swz_band(int bid, int per_xcd) {
    return (bid & 7) * per_xcd + (bid >> 3);
}

// ---------------- Kernel 0: fold BN into weights, precompute xnorm affine ----------------
__global__ void k_setup(
    const float* __restrict__ dmin, const float* __restrict__ dmax,
    const float* __restrict__ w0, const float* __restrict__ g0, const float* __restrict__ b0,
    const float* __restrict__ m0, const float* __restrict__ v0,
    const float* __restrict__ w1, const float* __restrict__ g1, const float* __restrict__ b1,
    const float* __restrict__ m1, const float* __restrict__ v1,
    const float* __restrict__ w2, const float* __restrict__ b2,
    float* __restrict__ ws)
{
    int t = threadIdx.x;
    if (t < 16) {
        float inv   = g0[t] * rsqrtf(v0[t] + BN_EPS);
        float shift = b0[t] - m0[t] * inv;
        for (int g = 0; g < G_; ++g) ws[t * G_ + g] = w0[t * G_ + g] * inv;
        ws[128 + t] = shift;
    }
    if (t < 8) {
        float inv   = g1[t] * rsqrtf(v1[t] + BN_EPS);
        float shift = b1[t] - m1[t] * inv;
        for (int i = 0; i < 16; ++i) ws[144 + t * 16 + i] = w1[t * 16 + i] * inv;
        ws[272 + t] = shift;
        ws[280 + t] = w2[t];
    }
    if (t == 0) ws[288] = b2[0];
    if (t < B_) {
        float imin = 1.0f / dmin[t];
        float imax = 1.0f / dmax[t];
        float sc   = 1.0f / (imin - imax);
        ws[292 + t] = sc;
        ws[296 + t] = -imax * sc;
    }
}

// ---------------- MLP for one pixel-depth: G costs -> s ----------------
__device__ __forceinline__ float mlp_eval(const float c[G_], const float* __restrict__ ws) {
    float h0[16];
#pragma unroll
    for (int o = 0; o < 16; ++o) {
        float acc = ws[128 + o];
#pragma unroll
        for (int g = 0; g < G_; ++g) acc = fmaf(c[g], ws[o * G_ + g], acc);
        h0[o] = fmaxf(acc, 0.0f);
    }
    float h1[8];
#pragma unroll
    for (int o = 0; o < 8; ++o) {
        float acc = ws[272 + o];
#pragma unroll
        for (int i = 0; i < 16; ++i) acc = fmaf(h0[i], ws[144 + o * 16 + i], acc);
        h1[o] = fmaxf(acc, 0.0f);
    }
    float s = ws[288];
#pragma unroll
    for (int i = 0; i < 8; ++i) s = fmaf(h1[i], ws[280 + i], s);
    return s;
}

// ---------------- Kernel 1: one thread per (pixel, depth-pair) ----------------
// tid = (b*HW + pix) * 4 + j, handles depths 2j and 2j+1, writes plane[j].
// 5120 blocks: XCD k covers pixels [k*40960, (k+1)*40960) — same bands as k_aggregate.
__global__ __launch_bounds__(256) void k_s_xnorm(
    const float* __restrict__ cost,      // [B,G,D,H,W]
    const float* __restrict__ dsamp,     // [B,D,H,W]
    const float* __restrict__ ws,
    float4* __restrict__ plane)          // [4][B*HW]
{
    int tid = swz_band(blockIdx.x, 640) * 256 + threadIdx.x;  // over B*HW*4
    int j   = tid & 3;
    int idx = tid >> 2;          // b*HW + pix
    int b   = idx / HW;
    int pix = idx % HW;
    int d0  = j * 2;

    float sc  = ws[292 + b];
    float ofs = ws[296 + b];

    const float* cb = cost  + (size_t)b * G_ * DHW + (size_t)d0 * HW + pix;
    const float* db = dsamp + (size_t)b * DHW + (size_t)d0 * HW + pix;

    float c0[G_], c1[G_];
#pragma unroll
    for (int g = 0; g < G_; ++g) {
        c0[g] = cb[(size_t)g * DHW];
        c1[g] = cb[(size_t)g * DHW + HW];
    }

    float s0 = mlp_eval(c0, ws);
    float s1 = mlp_eval(c1, ws);

    float4 res;
    res.x = fmaf(__builtin_amdgcn_rcpf(db[0]),  sc, ofs);
    res.y = s0;
    res.z = fmaf(__builtin_amdgcn_rcpf(db[HW]), sc, ofs);
    res.w = s1;

    plane[(size_t)j * BHW + idx] = res;
}

// ---------------- Kernel 2: neighbor gather + sigmoid kernel + aggregate ----------------
__global__ __launch_bounds__(256) void k_aggregate(
    const float* __restrict__ grid,      // [B, N*H, W, 2]
    const float* __restrict__ fweight,   // [B, N, H, W]
    const float4* __restrict__ plane,    // [4][B*HW]
    float* __restrict__ out)             // [B,D,H,W]
{
    int idx = swz_band(blockIdx.x, 160) * 256 + threadIdx.x;  // b*HW + pix
    int b   = idx / HW;
    int pix = idx % HW;
    int h   = pix / W_;
    int wq  = pix % W_;

    // center xnorm per depth (one coalesced float4 per plane)
    float xnc[D_];
#pragma unroll
    for (int j = 0; j < 4; ++j) {
        float4 v = plane[(size_t)j * BHW + idx];
        xnc[2 * j]     = v.x;
        xnc[2 * j + 1] = v.z;
    }

    float acc[D_];
#pragma unroll
    for (int d = 0; d < D_; ++d) acc[d] = 0.0f;

    const float2* gp = (const float2*)grid;
    const int bbase = b * HW;

    for (int n = 0; n < N_; ++n) {
        float2 g = gp[(b * (N_ * H_) + n * H_ + h) * W_ + wq];
        // align_corners=False, border padding
        float gxp = fminf(fmaxf((g.x + 1.0f) * 0.5f * W_ - 0.5f, 0.0f), (float)(W_ - 1));
        float gyp = fminf(fmaxf((g.y + 1.0f) * 0.5f * H_ - 0.5f, 0.0f), (float)(H_ - 1));
        float x0f = floorf(gxp);
        float y0f = floorf(gyp);
        float wx = gxp - x0f;
        float wy = gyp - y0f;
        int x0 = (int)x0f;
        int y0 = (int)y0f;
        int x1 = min(x0 + 1, W_ - 1);
        int y1 = min(y0 + 1, H_ - 1);
        float w00 = (1.0f - wx) * (1.0f - wy);
        float w01 = wx * (1.0f - wy);
        float w10 = (1.0f - wx) * wy;
        float w11 = wx * wy;

        float fw = fweight[((b * N_ + n) * H_ + h) * W_ + wq];

        int o00 = bbase + y0 * W_ + x0;
        int o01 = bbase + y0 * W_ + x1;
        int o10 = bbase + y1 * W_ + x0;
        int o11 = bbase + y1 * W_ + x1;

#pragma unroll
        for (int j = 0; j < 4; ++j) {
            const float4* pj = plane + (size_t)j * BHW;
            float4 a = pj[o00];
            float4 p = pj[o01];
            float4 q = pj[o10];
            float4 r = pj[o11];
            // depth 2j: components .x (xn), .y (s); depth 2j+1: .z, .w
            float xs0 = w00 * a.x + w01 * p.x + w10 * q.x + w11 * r.x;
            float ss0 = w00 * a.y + w01 * p.y + w10 * q.y + w11 * r.y;
            float xs1 = w00 * a.z + w01 * p.z + w10 * q.z + w11 * r.z;
            float ss1 = w00 * a.w + w01 * p.w + w10 * q.w + w11 * r.w;

            float df0 = fminf(fabsf(xs0 - xnc[2 * j]) * 40.0f, 4.0f);
            float df1 = fminf(fabsf(xs1 - xnc[2 * j + 1]) * 40.0f, 4.0f);
            float dw0 = __builtin_amdgcn_rcpf(1.0f + __expf(2.0f * df0 - 4.0f));
            float dw1 = __builtin_amdgcn_rcpf(1.0f + __expf(2.0f * df1 - 4.0f));
            acc[2 * j]     = fmaf(ss0 * fw, dw0, acc[2 * j]);
            acc[2 * j + 1] = fmaf(ss1 * fw, dw1, acc[2 * j + 1]);
        }
    }

#pragma unroll
    for (int d = 0; d < D_; ++d) out[(b * D_ + d) * HW + pix] = acc[d];
}

extern "C" void kernel_launch(void* const* d_in, const int* in_sizes, int n_in,
                              void* d_out, int out_size, void* d_ws, size_t ws_size,
                              hipStream_t stream) {
    const float* cost    = (const float*)d_in[0];
    const float* dsamp   = (const float*)d_in[1];
    const float* dmin    = (const float*)d_in[2];
    const float* dmax    = (const float*)d_in[3];
    const float* grid    = (const float*)d_in[4];
    const float* fweight = (const float*)d_in[5];
    const float* w0 = (const float*)d_in[6];
    const float* g0 = (const float*)d_in[7];
    const float* b0 = (const float*)d_in[8];
    const float* m0 = (const float*)d_in[9];
    const float* v0 = (const float*)d_in[10];
    const float* w1 = (const float*)d_in[11];
    const float* g1 = (const float*)d_in[12];
    const float* b1 = (const float*)d_in[13];
    const float* m1 = (const float*)d_in[14];
    const float* v1 = (const float*)d_in[15];
    const float* w2 = (const float*)d_in[16];
    const float* b2 = (const float*)d_in[17];
    float* out = (float*)d_out;

    float*  ws    = (float*)d_ws;
    float4* plane = (float4*)(ws + WS_PAIR_OFF);

    k_setup<<<1, 64, 0, stream>>>(dmin, dmax,
                                  w0, g0, b0, m0, v0,
                                  w1, g1, b1, m1, v1,
                                  w2, b2, ws);

    // k1: 5120 blocks over (pixel, depth-pair); k2: 1280 blocks over pixels.
    // Both map pixel p -> XCD p/40960, so the XCD that writes a pair band
    // is the XCD that gathers from it.
    k_s_xnorm<<<5120, 256, 0, stream>>>(cost, dsamp, ws, plane);
    k_aggregate<<<1280, 256, 0, stream>>>(grid, fweight, plane, out);
}